// Round 1
// 254.212 us; speedup vs baseline: 1.0224x; 1.0224x over previous
//
#include <hip/hip_runtime.h>
#include <math.h>

#define S_LEN 4096
#define HIDN  1024
#define NH    16
#define HD    64
#define BATCH 2
#define M_TOTAL (BATCH * S_LEN)   // 8192
#define N_RKV   (3 * HIDN)        // 3072
#define CS 128
#define NC (S_LEN / CS)           // 32

typedef __attribute__((ext_vector_type(8))) _Float16 f16x8;
typedef __attribute__((ext_vector_type(4))) float f32x4;
typedef __attribute__((ext_vector_type(4))) unsigned short u16x4;

// ---------- fp16 convert ----------
__device__ __forceinline__ unsigned short f2h(float x) {
    _Float16 h = (_Float16)x;
    return *(unsigned short*)&h;
}
__device__ __forceinline__ float h2f(unsigned short b) {
    _Float16 h = *(_Float16*)&b;
    return (float)h;
}

// ---------- async global->LDS, 16B per lane ----------
__device__ __forceinline__ void load_lds16(const void* g, void* l) {
    __builtin_amdgcn_global_load_lds((const __attribute__((address_space(1))) void*)g,
                                     (__attribute__((address_space(3))) void*)l, 16, 0, 0);
}

// ---------- K0: a = mean(exp(time_decay)) ----------
__global__ void k_avg_decay(const float* __restrict__ td, float* __restrict__ a_out) {
    int t = threadIdx.x;
    double acc = 0.0;
    for (int i = t; i < NH * HD; i += 64) acc += exp((double)td[i]);
    for (int off = 32; off > 0; off >>= 1) acc += __shfl_down(acc, off, 64);
    if (t == 0) a_out[0] = (float)(acc / (double)(NH * HD));
}

// ---------- K1a: mixed = hs*tm + shift(hs)*(1-tm) -> fp16 ----------
__global__ __launch_bounds__(256)
void k_split_mix(const float* __restrict__ hs, const float* __restrict__ tm,
                 unsigned short* __restrict__ Ah) {
    int g = blockIdx.x * 256 + threadIdx.x;      // over M_TOTAL * (HIDN/4)
    int kc = (g & 255) * 4;
    int m = g >> 8;
    float4 cur = *(const float4*)&hs[(size_t)m * HIDN + kc];
    float4 t4  = *(const float4*)&tm[kc];
    float4 prev = make_float4(0.f, 0.f, 0.f, 0.f);
    if (m & (S_LEN - 1)) prev = *(const float4*)&hs[(size_t)(m - 1) * HIDN + kc];
    u16x4 h;
    h.x = f2h(cur.x * t4.x + prev.x * (1.f - t4.x));
    h.y = f2h(cur.y * t4.y + prev.y * (1.f - t4.y));
    h.z = f2h(cur.z * t4.z + prev.z * (1.f - t4.z));
    h.w = f2h(cur.w * t4.w + prev.w * (1.f - t4.w));
    *(u16x4*)&Ah[(size_t)m * HIDN + kc] = h;
}

// ---------- K1b: flat fp32 -> fp16 (weights) ----------
__global__ __launch_bounds__(256)
void k_split_w(const float* __restrict__ W, unsigned short* __restrict__ Wh) {
    int g = blockIdx.x * 256 + threadIdx.x;
    size_t o = (size_t)g * 4;
    float4 v = *(const float4*)&W[o];
    u16x4 h;
    h.x = f2h(v.x); h.y = f2h(v.y); h.z = f2h(v.z); h.w = f2h(v.w);
    *(u16x4*)&Wh[o] = h;
}

__device__ __forceinline__ f32x4 mfma16(f16x8 a, f16x8 b, f32x4 c) {
    return __builtin_amdgcn_mfma_f32_16x16x32_f16(a, b, c, 0, 0, 0);
}

// ---------- unified B^T MFMA GEMM: C[M x LDC] = A[M x 1024] * Bm[N x 1024]^T ----------
// 128x128 tile, 256 threads / 4 waves (2x2), 64x64 per wave, double-buffered
// global_load_lds staging (2 x 16 KB), one barrier per K-step, XCD-swizzled grid.
template<int LDC, int NBX, bool HALF_OUT>
__global__ __launch_bounds__(256, 2)
void k_gemm_bt(const unsigned short* __restrict__ A,
               const unsigned short* __restrict__ Bm,
               void* __restrict__ Cv)
{
    __shared__ unsigned short smem[16384];       // 32 KB: two 8192-elem buffers
    const int tid  = threadIdx.x;
    const int lane = tid & 63;
    const int wave = tid >> 6;
    const int wm = wave >> 1, wn = wave & 1;

    // bijective XCD-aware swizzle (gridDim.x % 8 == 0 guaranteed by launch)
    const int cpx = gridDim.x >> 3;
    const int wg  = (blockIdx.x & 7) * cpx + (blockIdx.x >> 3);
    const int bx  = wg % NBX;
    const int by  = wg / NBX;
    const int m0 = by * 128;
    const int n0 = bx * 128;

    // staging: 16 segments (16 rows x 32 k, 1 KB each); wave handles 4
    const unsigned short* segsrc[4];
    int segdst[4];
    {
        int rowoff = lane >> 2;
        int q = (lane & 3) ^ (rowoff & 3);
#pragma unroll
        for (int i = 0; i < 4; ++i) {
            int s = wave * 4 + i;
            const unsigned short* base = (s < 8) ? A : Bm;
            int row = (s < 8) ? (m0 + s * 16) : (n0 + (s - 8) * 16);
            segsrc[i] = base + (size_t)(row + rowoff) * 1024 + q * 8;
            segdst[i] = s * 512;
        }
    }

    const int lm = lane & 15;
    const int rq = lane >> 4;
    const int qx = rq ^ (lane & 3);
    int aoff[4], boff[4];
#pragma unroll
    for (int t = 0; t < 4; ++t) {
        aoff[t] = (wm * 64 + t * 16 + lm) * 32 + qx * 8;
        boff[t] = 4096 + (wn * 64 + t * 16 + lm) * 32 + qx * 8;
    }

    f32x4 acc[4][4] = {};

    // prologue: stage kt=0 into buffer 0
#pragma unroll
    for (int i = 0; i < 4; ++i) load_lds16(segsrc[i], smem + segdst[i]);

    int p = 0;
    for (int kt = 0; kt < 1024; kt += 32) {
        __syncthreads();                         // buffer p staged; old readers done
        if (kt + 32 < 1024) {
#pragma unroll
            for (int i = 0; i < 4; ++i)
                load_lds16(segsrc[i] + kt + 32, smem + ((p ^ 1) * 8192 + segdst[i]));
        }
        const unsigned short* sb = smem + p * 8192;
        f16x8 fa[4], fb[4];
#pragma unroll
        for (int t = 0; t < 4; ++t) {
            fa[t] = *(const f16x8*)(sb + aoff[t]);
            fb[t] = *(const f16x8*)(sb + boff[t]);
        }
#pragma unroll
        for (int mt = 0; mt < 4; ++mt)
#pragma unroll
            for (int nt = 0; nt < 4; ++nt)
                acc[mt][nt] = mfma16(fa[mt], fb[nt], acc[mt][nt]);
        p ^= 1;
    }

#pragma unroll
    for (int mt = 0; mt < 4; ++mt)
#pragma unroll
        for (int nt = 0; nt < 4; ++nt) {
            int col = n0 + wn * 64 + nt * 16 + lm;
#pragma unroll
            for (int r = 0; r < 4; ++r) {
                int row = m0 + wm * 64 + mt * 16 + rq * 4 + r;
                if constexpr (HALF_OUT)
                    ((unsigned short*)Cv)[(size_t)row * LDC + col] = f2h(acc[mt][nt][r]);
                else
                    ((float*)Cv)[(size_t)row * LDC + col] = acc[mt][nt][r];
            }
        }
}

// ---------- K3: chunk decay sums Cb from rkv (RoPE'd k * v) ----------
// block = (bh, chunk). 256 threads: lane&15 -> d-group of 4, lane>>4 -> row slot,
// wave -> 32-row group. Vectorized 8B fp16 loads; RoPE pair d^32 via shfl_xor(8).
__global__ __launch_bounds__(256)
void k_cb(const unsigned short* __restrict__ rkv,
          const float* __restrict__ cosp, const float* __restrict__ sinp,
          const float* __restrict__ a_ptr, float* __restrict__ Cb)
{
    __shared__ float Ls[4][64][4];
    int bid = blockIdx.x;                        // bh*NC + c
    int c  = bid & (NC - 1);
    int bh = bid >> 5;
    int b = bh >> 4, h = bh & 15;
    int lane = threadIdx.x & 63;
    int wave = threadIdx.x >> 6;
    int lm = lane & 15;
    int rs = lane >> 4;
    int d0 = lm * 4;
    float a = a_ptr[0];
    float sgn = (lm < 8) ? -1.f : 1.f;
    float ps0 = 0.f, ps1 = 0.f, ps2 = 0.f, ps3 = 0.f;
#pragma unroll
    for (int it = 0; it < 8; ++it) {
        int t = wave * 32 + it * 4 + rs;         // in-chunk row 0..127
        int s = c * CS + t;
        const unsigned short* rk = rkv + ((size_t)b * S_LEN + s) * N_RKV + h * 64 + d0;
        u16x4 k4 = *(const u16x4*)(rk + 1024);
        u16x4 v4 = *(const u16x4*)(rk + 2048);
        float4 cs4 = *(const float4*)&cosp[s * HD + d0];
        float4 sn4 = *(const float4*)&sinp[s * HD + d0];
        float e = expf(a * (float)t);
        float k0 = h2f(k4.x), k1 = h2f(k4.y), k2 = h2f(k4.z), k3 = h2f(k4.w);
        float kp0 = __shfl_xor(k0, 8, 64);
        float kp1 = __shfl_xor(k1, 8, 64);
        float kp2 = __shfl_xor(k2, 8, 64);
        float kp3 = __shfl_xor(k3, 8, 64);
        ps0 += e * (k0 * cs4.x + sgn * kp0 * sn4.x) * h2f(v4.x);
        ps1 += e * (k1 * cs4.y + sgn * kp1 * sn4.y) * h2f(v4.y);
        ps2 += e * (k2 * cs4.z + sgn * kp2 * sn4.z) * h2f(v4.z);
        ps3 += e * (k3 * cs4.w + sgn * kp3 * sn4.w) * h2f(v4.w);
    }
    Ls[wave][lane][0] = ps0; Ls[wave][lane][1] = ps1;
    Ls[wave][lane][2] = ps2; Ls[wave][lane][3] = ps3;
    __syncthreads();
    if (threadIdx.x < 64) {
        int d = threadIdx.x;
        int lmm = d >> 2, j = d & 3;
        float sum = 0.f;
#pragma unroll
        for (int wv = 0; wv < 4; ++wv)
#pragma unroll
            for (int r = 0; r < 4; ++r)
                sum += Ls[wv][r * 16 + lmm][j];
        Cb[((size_t)bh * NC + c) * 64 + d] = sum;
    }
}

// ---------- K5: exclusive chunk suffix ----------
__global__ __launch_bounds__(64)
void k_chunk_suffix(const float* __restrict__ Cb, const float* __restrict__ a_ptr,
                    float* __restrict__ Sb) {
    int bh = blockIdx.x;
    int d = threadIdx.x;
    float a = a_ptr[0];
    float eaCS = expf(a * (float)CS);
    float run = 0.f;
    Sb[(size_t)(bh * NC + NC - 1) * 64 + d] = 0.f;
    for (int c = NC - 2; c >= 0; --c) {
        run = Cb[(size_t)(bh * NC + c + 1) * 64 + d] + eaCS * run;
        Sb[(size_t)(bh * NC + c) * 64 + d] = run;
    }
}

// ---------- K6: in-chunk suffix scan + epilogue, reading rkv directly ----------
// Recomputes sigmoid+RoPE+kv in registers (r, kv stay fp32 -> no rP/kvP round-trip).
__global__ __launch_bounds__(256)
void k_wkv2(const unsigned short* __restrict__ rkv,
            const float* __restrict__ cosp, const float* __restrict__ sinp,
            const float* __restrict__ Sb, const float* __restrict__ a_ptr,
            const float* __restrict__ tf,
            unsigned short* __restrict__ outH) {
    __shared__ float Tl[4][64];
    int bid = blockIdx.x;                // bh*NC + c
    int c  = bid & (NC - 1);
    int bh = bid >> 5;
    int b = bh >> 4, h = bh & 15;
    int lane = threadIdx.x & 63;
    int wave = threadIdx.x >> 6;
    float a = a_ptr[0];
    float ea = expf(a);
    float em1a = expm1f(a);
    int s0 = c * CS + wave * 32;
    const unsigned short* rkb = rkv + ((size_t)b * S_LEN + s0) * N_RKV + h * 64 + lane;
    float sgn = (lane < 32) ? -1.f : 1.f;

    float kvreg[32], rreg[32];
    float w = 1.f, T = 0.f;
#pragma unroll
    for (int t = 0; t < 32; ++t) {
        const unsigned short* pr = rkb + (size_t)t * N_RKV;
        float r_ = h2f(pr[0]);
        float k_ = h2f(pr[1024]);
        float v_ = h2f(pr[2048]);
        float cs = cosp[(s0 + t) * HD + lane];
        float sn = sinp[(s0 + t) * HD + lane];
        float sig = 1.f / (1.f + expf(-r_));
        float sigp = __shfl_xor(sig, 32, 64);
        float kp   = __shfl_xor(k_, 32, 64);
        rreg[t]  = sig * cs + sgn * sigp * sn;
        kvreg[t] = (k_ * cs + sgn * kp * sn) * v_;
        T += w * kvreg[t];
        w *= ea;
    }
    Tl[wave][lane] = T;
    __syncthreads();

    float e32 = expf(a * 32.f);
    float S_run = Sb[(size_t)bid * 64 + lane] * expf(a * 32.f * (float)(3 - wave));
    float f = 1.f;
    for (int wp = wave + 1; wp < 4; ++wp) {
        S_run += f * Tl[wp][lane];
        f *= e32;
    }
    float tfv = tf[h * HD + lane];
#pragma unroll
    for (int t = 31; t >= 0; --t) {
        float kv = kvreg[t];
        S_run = kv + ea * S_run;
        int ig = c * CS + wave * 32 + t;
        float Z = expm1f(a * (float)(S_LEN - ig)) / em1a + 1e-8f;
        float o = rreg[t] * (tfv * kv + S_run / Z);
        size_t m = (size_t)b * S_LEN + ig;
        outH[m * HIDN + h * HD + lane] = f2h(o);
    }
}

extern "C" void kernel_launch(void* const* d_in, const int* in_sizes, int n_in,
                              void* d_out, int out_size, void* d_ws, size_t ws_size,
                              hipStream_t stream) {
    const float* hs    = (const float*)d_in[0];
    const float* cosp  = (const float*)d_in[1];
    const float* sinp  = (const float*)d_in[2];
    const float* W_rkv = (const float*)d_in[3];
    const float* W_o   = (const float*)d_in[4];
    const float* td    = (const float*)d_in[5];
    const float* tf    = (const float*)d_in[6];
    const float* tm    = (const float*)d_in[7];
    float* out = (float*)d_out;

    // workspace layout (total 76,021,764 B — identical footprint to prior version)
    char* w = (char*)d_ws;
    unsigned short* rkvH = (unsigned short*)w;                    // 48 MiB [gemm1 -> cb,wkv2]
    unsigned short* Ah   = (unsigned short*)(w + 50331648);       // 16 MiB [mix -> gemm1]
    unsigned short* outH = (unsigned short*)(w + 50331648);       // aliases Ah (dead after gemm1)
    unsigned short* Wrh  = (unsigned short*)(w + 67108864);       // 6 MiB
    unsigned short* Woh  = (unsigned short*)(w + 73400320);       // 2 MiB
    float*          Cb   = (float*)(w + 75497472);                // 256 KiB
    float*          Sb   = (float*)(w + 75759616);                // 256 KiB
    float*          a_ptr= (float*)(w + 76021760);                // 4 B

    k_avg_decay<<<1, 64, 0, stream>>>(td, a_ptr);

    k_split_mix<<<(M_TOTAL * HIDN / 4) / 256, 256, 0, stream>>>(hs, tm, Ah);
    k_split_w<<<(N_RKV * HIDN / 4) / 256, 256, 0, stream>>>(W_rkv, Wrh);
    k_split_w<<<(HIDN * HIDN / 4) / 256, 256, 0, stream>>>(W_o, Woh);

    // GEMM1: rkv = Ah(8192x1024) * Wrh(3072x1024)^T  -> fp16
    k_gemm_bt<N_RKV, 24, true><<<1536, 256, 0, stream>>>(Ah, Wrh, rkvH);

    k_cb<<<BATCH * NH * NC, 256, 0, stream>>>(rkvH, cosp, sinp, a_ptr, Cb);
    k_chunk_suffix<<<BATCH * NH, 64, 0, stream>>>(Cb, a_ptr, Sb);
    k_wkv2<<<BATCH * NH * NC, 256, 0, stream>>>(rkvH, cosp, sinp, Sb, a_ptr, tf, outH);

    // GEMM2: out = outH(8192x1024) * Woh(1024x1024)^T -> fp32
    k_gemm_bt<HIDN, 8, false><<<512, 256, 0, stream>>>(outH, Woh, out);
}

// Round 2
// 239.825 us; speedup vs baseline: 1.0837x; 1.0600x over previous
//
#include <hip/hip_runtime.h>
#include <math.h>

#define S_LEN 4096
#define HIDN  1024
#define NH    16
#define HD    64
#define BATCH 2
#define M_TOTAL (BATCH * S_LEN)   // 8192
#define N_RKV   (3 * HIDN)        // 3072
#define CS 128
#define NC (S_LEN / CS)           // 32

typedef __attribute__((ext_vector_type(8))) _Float16 f16x8;
typedef __attribute__((ext_vector_type(4))) float f32x4;
typedef __attribute__((ext_vector_type(4))) unsigned short u16x4;

// ---------- fp16 convert ----------
__device__ __forceinline__ unsigned short f2h(float x) {
    _Float16 h = (_Float16)x;
    return *(unsigned short*)&h;
}
__device__ __forceinline__ float h2f(unsigned short b) {
    _Float16 h = *(_Float16*)&b;
    return (float)h;
}

// ---------- async global->LDS, 16B per lane ----------
__device__ __forceinline__ void load_lds16(const void* g, void* l) {
    __builtin_amdgcn_global_load_lds((const __attribute__((address_space(1))) void*)g,
                                     (__attribute__((address_space(3))) void*)l, 16, 0, 0);
}

// ---------- K0: a = mean(exp(time_decay)) ----------
__global__ void k_avg_decay(const float* __restrict__ td, float* __restrict__ a_out) {
    int t = threadIdx.x;
    double acc = 0.0;
    for (int i = t; i < NH * HD; i += 64) acc += exp((double)td[i]);
    for (int off = 32; off > 0; off >>= 1) acc += __shfl_down(acc, off, 64);
    if (t == 0) a_out[0] = (float)(acc / (double)(NH * HD));
}

// ---------- K1a: mixed = hs*tm + shift(hs)*(1-tm) -> fp16 ----------
__global__ __launch_bounds__(256)
void k_split_mix(const float* __restrict__ hs, const float* __restrict__ tm,
                 unsigned short* __restrict__ Ah) {
    int g = blockIdx.x * 256 + threadIdx.x;      // over M_TOTAL * (HIDN/4)
    int kc = (g & 255) * 4;
    int m = g >> 8;
    float4 cur = *(const float4*)&hs[(size_t)m * HIDN + kc];
    float4 t4  = *(const float4*)&tm[kc];
    float4 prev = make_float4(0.f, 0.f, 0.f, 0.f);
    if (m & (S_LEN - 1)) prev = *(const float4*)&hs[(size_t)(m - 1) * HIDN + kc];
    u16x4 h;
    h.x = f2h(cur.x * t4.x + prev.x * (1.f - t4.x));
    h.y = f2h(cur.y * t4.y + prev.y * (1.f - t4.y));
    h.z = f2h(cur.z * t4.z + prev.z * (1.f - t4.z));
    h.w = f2h(cur.w * t4.w + prev.w * (1.f - t4.w));
    *(u16x4*)&Ah[(size_t)m * HIDN + kc] = h;
}

// ---------- K1b: flat fp32 -> fp16 (weights) ----------
__global__ __launch_bounds__(256)
void k_split_w(const float* __restrict__ W, unsigned short* __restrict__ Wh) {
    int g = blockIdx.x * 256 + threadIdx.x;
    size_t o = (size_t)g * 4;
    float4 v = *(const float4*)&W[o];
    u16x4 h;
    h.x = f2h(v.x); h.y = f2h(v.y); h.z = f2h(v.z); h.w = f2h(v.w);
    *(u16x4*)&Wh[o] = h;
}

__device__ __forceinline__ f32x4 mfma16(f16x8 a, f16x8 b, f32x4 c) {
    return __builtin_amdgcn_mfma_f32_16x16x32_f16(a, b, c, 0, 0, 0);
}

// ---------- unified B^T MFMA GEMM: C[M x LDC] = A[M x 1024] * Bm[N x 1024]^T ----------
// 128x128 tile, 256 threads / 4 waves (2x2), 64x64 per wave, double-buffered
// global_load_lds staging (2 x 16 KB), one barrier per K-step, XCD-swizzled grid.
template<int LDC, int NBX, bool HALF_OUT>
__global__ __launch_bounds__(256, 2)
void k_gemm_bt(const unsigned short* __restrict__ A,
               const unsigned short* __restrict__ Bm,
               void* __restrict__ Cv)
{
    __shared__ unsigned short smem[16384];       // 32 KB: two 8192-elem buffers
    const int tid  = threadIdx.x;
    const int lane = tid & 63;
    const int wave = tid >> 6;
    const int wm = wave >> 1, wn = wave & 1;

    // bijective XCD-aware swizzle (gridDim.x % 8 == 0 guaranteed by launch)
    const int cpx = gridDim.x >> 3;
    const int wg  = (blockIdx.x & 7) * cpx + (blockIdx.x >> 3);
    const int bx  = wg % NBX;
    const int by  = wg / NBX;
    const int m0 = by * 128;
    const int n0 = bx * 128;

    // staging: 16 segments (16 rows x 32 k, 1 KB each); wave handles 4
    const unsigned short* segsrc[4];
    int segdst[4];
    {
        int rowoff = lane >> 2;
        int q = (lane & 3) ^ (rowoff & 3);
#pragma unroll
        for (int i = 0; i < 4; ++i) {
            int s = wave * 4 + i;
            const unsigned short* base = (s < 8) ? A : Bm;
            int row = (s < 8) ? (m0 + s * 16) : (n0 + (s - 8) * 16);
            segsrc[i] = base + (size_t)(row + rowoff) * 1024 + q * 8;
            segdst[i] = s * 512;
        }
    }

    const int lm = lane & 15;
    const int rq = lane >> 4;
    const int qx = rq ^ (lane & 3);
    int aoff[4], boff[4];
#pragma unroll
    for (int t = 0; t < 4; ++t) {
        aoff[t] = (wm * 64 + t * 16 + lm) * 32 + qx * 8;
        boff[t] = 4096 + (wn * 64 + t * 16 + lm) * 32 + qx * 8;
    }

    f32x4 acc[4][4] = {};

    // prologue: stage kt=0 into buffer 0
#pragma unroll
    for (int i = 0; i < 4; ++i) load_lds16(segsrc[i], smem + segdst[i]);

    int p = 0;
    for (int kt = 0; kt < 1024; kt += 32) {
        __syncthreads();                         // buffer p staged; old readers done
        if (kt + 32 < 1024) {
#pragma unroll
            for (int i = 0; i < 4; ++i)
                load_lds16(segsrc[i] + kt + 32, smem + ((p ^ 1) * 8192 + segdst[i]));
        }
        const unsigned short* sb = smem + p * 8192;
        f16x8 fa[4], fb[4];
#pragma unroll
        for (int t = 0; t < 4; ++t) {
            fa[t] = *(const f16x8*)(sb + aoff[t]);
            fb[t] = *(const f16x8*)(sb + boff[t]);
        }
#pragma unroll
        for (int mt = 0; mt < 4; ++mt)
#pragma unroll
            for (int nt = 0; nt < 4; ++nt)
                acc[mt][nt] = mfma16(fa[mt], fb[nt], acc[mt][nt]);
        p ^= 1;
    }

#pragma unroll
    for (int mt = 0; mt < 4; ++mt)
#pragma unroll
        for (int nt = 0; nt < 4; ++nt) {
            int col = n0 + wn * 64 + nt * 16 + lm;
#pragma unroll
            for (int r = 0; r < 4; ++r) {
                int row = m0 + wm * 64 + mt * 16 + rq * 4 + r;
                if constexpr (HALF_OUT)
                    ((unsigned short*)Cv)[(size_t)row * LDC + col] = f2h(acc[mt][nt][r]);
                else
                    ((float*)Cv)[(size_t)row * LDC + col] = acc[mt][nt][r];
            }
        }
}

// ---------- K3: chunk decay sums Cb from rkv (RoPE'd k * v) ----------
__global__ __launch_bounds__(256)
void k_cb(const unsigned short* __restrict__ rkv,
          const float* __restrict__ cosp, const float* __restrict__ sinp,
          const float* __restrict__ a_ptr, float* __restrict__ Cb)
{
    __shared__ float Ls[4][64][4];
    int bid = blockIdx.x;                        // bh*NC + c
    int c  = bid & (NC - 1);
    int bh = bid >> 5;
    int b = bh >> 4, h = bh & 15;
    int lane = threadIdx.x & 63;
    int wave = threadIdx.x >> 6;
    int lm = lane & 15;
    int rs = lane >> 4;
    int d0 = lm * 4;
    float a = a_ptr[0];
    float sgn = (lm < 8) ? -1.f : 1.f;
    float ps0 = 0.f, ps1 = 0.f, ps2 = 0.f, ps3 = 0.f;
#pragma unroll
    for (int it = 0; it < 8; ++it) {
        int t = wave * 32 + it * 4 + rs;         // in-chunk row 0..127
        int s = c * CS + t;
        const unsigned short* rk = rkv + ((size_t)b * S_LEN + s) * N_RKV + h * 64 + d0;
        u16x4 k4 = *(const u16x4*)(rk + 1024);
        u16x4 v4 = *(const u16x4*)(rk + 2048);
        float4 cs4 = *(const float4*)&cosp[s * HD + d0];
        float4 sn4 = *(const float4*)&sinp[s * HD + d0];
        float e = expf(a * (float)t);
        float k0 = h2f(k4.x), k1 = h2f(k4.y), k2 = h2f(k4.z), k3 = h2f(k4.w);
        float kp0 = __shfl_xor(k0, 8, 64);
        float kp1 = __shfl_xor(k1, 8, 64);
        float kp2 = __shfl_xor(k2, 8, 64);
        float kp3 = __shfl_xor(k3, 8, 64);
        ps0 += e * (k0 * cs4.x + sgn * kp0 * sn4.x) * h2f(v4.x);
        ps1 += e * (k1 * cs4.y + sgn * kp1 * sn4.y) * h2f(v4.y);
        ps2 += e * (k2 * cs4.z + sgn * kp2 * sn4.z) * h2f(v4.z);
        ps3 += e * (k3 * cs4.w + sgn * kp3 * sn4.w) * h2f(v4.w);
    }
    Ls[wave][lane][0] = ps0; Ls[wave][lane][1] = ps1;
    Ls[wave][lane][2] = ps2; Ls[wave][lane][3] = ps3;
    __syncthreads();
    if (threadIdx.x < 64) {
        int d = threadIdx.x;
        int lmm = d >> 2, j = d & 3;
        float sum = 0.f;
#pragma unroll
        for (int wv = 0; wv < 4; ++wv)
#pragma unroll
            for (int r = 0; r < 4; ++r)
                sum += Ls[wv][r * 16 + lmm][j];
        Cb[((size_t)bh * NC + c) * 64 + d] = sum;
    }
}

// ---------- K5: exclusive chunk suffix ----------
__global__ __launch_bounds__(64)
void k_chunk_suffix(const float* __restrict__ Cb, const float* __restrict__ a_ptr,
                    float* __restrict__ Sb) {
    int bh = blockIdx.x;
    int d = threadIdx.x;
    float a = a_ptr[0];
    float eaCS = expf(a * (float)CS);
    float run = 0.f;
    Sb[(size_t)(bh * NC + NC - 1) * 64 + d] = 0.f;
    for (int c = NC - 2; c >= 0; --c) {
        run = Cb[(size_t)(bh * NC + c + 1) * 64 + d] + eaCS * run;
        Sb[(size_t)(bh * NC + c) * 64 + d] = run;
    }
}

// ---------- K5b: Z normalizer table (depends only on global row index) ----------
__global__ __launch_bounds__(256)
void k_ztab(const float* __restrict__ a_ptr, float* __restrict__ Zt) {
    int i = blockIdx.x * 256 + threadIdx.x;
    if (i < S_LEN) {
        float a = a_ptr[0];
        float em1a = expm1f(a);
        Zt[i] = expm1f(a * (float)(S_LEN - i)) / em1a + 1e-8f;
    }
}

// ---------- K6: in-chunk suffix scan + epilogue, LDS-staged chunk tile ----------
// Stages r/k/v[128][64] fp16 (48 KB) via global_load_lds 16B/lane, then computes
// sigmoid+RoPE+kv from LDS (conflict-free 2B reads). Z loaded from precomputed table.
__global__ __launch_bounds__(256)
void k_wkv2(const unsigned short* __restrict__ rkv,
            const float* __restrict__ cosp, const float* __restrict__ sinp,
            const float* __restrict__ Sb, const float* __restrict__ a_ptr,
            const float* __restrict__ tf, const float* __restrict__ Zt,
            unsigned short* __restrict__ outH) {
    __shared__ unsigned short L[3 * 128 * 64];   // 48 KB: r,k,v tiles [row][d]
    __shared__ float Tl[4][64];
    int bid = blockIdx.x;                // bh*NC + c
    int c  = bid & (NC - 1);
    int bh = bid >> 5;
    int b = bh >> 4, h = bh & 15;
    int lane = threadIdx.x & 63;
    int wave = threadIdx.x >> 6;
    int s0 = c * CS;

    // stage: 48 segments of 1 KB (8 rows x 128 B of one stream); wave owns 12
#pragma unroll
    for (int i = 0; i < 12; ++i) {
        int seg = wave * 12 + i;         // 0..47
        int stream = seg >> 4;           // 0=r 1=k 2=v
        int rg = seg & 15;               // 8-row group
        int row = rg * 8 + (lane >> 3);
        const unsigned short* src = rkv
            + ((size_t)b * S_LEN + s0 + row) * N_RKV + stream * 1024 + h * 64
            + (lane & 7) * 8;
        load_lds16(src, L + stream * 8192 + rg * 512);   // HW scatters lane*16B
    }
    __syncthreads();                     // compiler drains vmcnt before barrier

    float a = a_ptr[0];
    float ea = expf(a);
    const unsigned short* Lr = L;
    const unsigned short* Lk = L + 8192;
    const unsigned short* Lv = L + 16384;
    float sgn = (lane < 32) ? -1.f : 1.f;
    int lx = lane ^ 32;

    float kvreg[32], rreg[32];
    float w = 1.f, T = 0.f;
#pragma unroll
    for (int t = 0; t < 32; ++t) {
        int row = wave * 32 + t;
        float r_ = h2f(Lr[row * 64 + lane]);
        float k_ = h2f(Lk[row * 64 + lane]);
        float kp = h2f(Lk[row * 64 + lx]);   // RoPE partner from LDS
        float v_ = h2f(Lv[row * 64 + lane]);
        float cs = cosp[(s0 + row) * HD + lane];
        float sn = sinp[(s0 + row) * HD + lane];
        float sig = 1.f / (1.f + expf(-r_));
        float sigp = __shfl_xor(sig, 32, 64);
        rreg[t]  = sig * cs + sgn * sigp * sn;
        kvreg[t] = (k_ * cs + sgn * kp * sn) * v_;
        T += w * kvreg[t];
        w *= ea;
    }
    Tl[wave][lane] = T;
    __syncthreads();

    float e32 = expf(a * 32.f);
    float S_run = Sb[(size_t)bid * 64 + lane] * expf(a * 32.f * (float)(3 - wave));
    float f = 1.f;
    for (int wp = wave + 1; wp < 4; ++wp) {
        S_run += f * Tl[wp][lane];
        f *= e32;
    }
    float tfv = tf[h * HD + lane];
#pragma unroll
    for (int t = 31; t >= 0; --t) {
        float kv = kvreg[t];
        S_run = kv + ea * S_run;
        int ig = s0 + wave * 32 + t;
        float Z = Zt[ig];                // identical arithmetic, hoisted to table
        float o = rreg[t] * (tfv * kv + S_run / Z);
        size_t m = (size_t)b * S_LEN + ig;
        outH[m * HIDN + h * HD + lane] = f2h(o);
    }
}

extern "C" void kernel_launch(void* const* d_in, const int* in_sizes, int n_in,
                              void* d_out, int out_size, void* d_ws, size_t ws_size,
                              hipStream_t stream) {
    const float* hs    = (const float*)d_in[0];
    const float* cosp  = (const float*)d_in[1];
    const float* sinp  = (const float*)d_in[2];
    const float* W_rkv = (const float*)d_in[3];
    const float* W_o   = (const float*)d_in[4];
    const float* td    = (const float*)d_in[5];
    const float* tf    = (const float*)d_in[6];
    const float* tm    = (const float*)d_in[7];
    float* out = (float*)d_out;

    // workspace layout (total 76,021,764 B — unchanged footprint)
    char* w = (char*)d_ws;
    unsigned short* rkvH = (unsigned short*)w;                    // 48 MiB [gemm1 -> cb,wkv2]
    unsigned short* Ah   = (unsigned short*)(w + 50331648);       // 16 MiB [mix -> gemm1]
    unsigned short* outH = (unsigned short*)(w + 50331648);       // aliases Ah (dead after gemm1)
    unsigned short* Wrh  = (unsigned short*)(w + 67108864);       // 6 MiB
    unsigned short* Woh  = (unsigned short*)(w + 73400320);       // 2 MiB
    float*          Cb   = (float*)(w + 75497472);                // 256 KiB
    float*          Sb   = (float*)(w + 75759616);                // 256 KiB
    float*          a_ptr= (float*)(w + 76021760);                // 4 B
    float*          Zt   = Cb;   // 16 KiB table; Cb dead after k_chunk_suffix

    k_avg_decay<<<1, 64, 0, stream>>>(td, a_ptr);

    k_split_mix<<<(M_TOTAL * HIDN / 4) / 256, 256, 0, stream>>>(hs, tm, Ah);
    k_split_w<<<(N_RKV * HIDN / 4) / 256, 256, 0, stream>>>(W_rkv, Wrh);
    k_split_w<<<(HIDN * HIDN / 4) / 256, 256, 0, stream>>>(W_o, Woh);

    // GEMM1: rkv = Ah(8192x1024) * Wrh(3072x1024)^T  -> fp16
    k_gemm_bt<N_RKV, 24, true><<<1536, 256, 0, stream>>>(Ah, Wrh, rkvH);

    k_cb<<<BATCH * NH * NC, 256, 0, stream>>>(rkvH, cosp, sinp, a_ptr, Cb);
    k_chunk_suffix<<<BATCH * NH, 64, 0, stream>>>(Cb, a_ptr, Sb);
    k_ztab<<<S_LEN / 256, 256, 0, stream>>>(a_ptr, Zt);
    k_wkv2<<<BATCH * NH * NC, 256, 0, stream>>>(rkvH, cosp, sinp, Sb, a_ptr, tf, Zt, outH);

    // GEMM2: out = outH(8192x1024) * Woh(1024x1024)^T -> fp32
    k_gemm_bt<HIDN, 8, false><<<512, 256, 0, stream>>>(outH, Woh, out);
}

// Round 3
// 232.607 us; speedup vs baseline: 1.1174x; 1.0310x over previous
//
#include <hip/hip_runtime.h>
#include <math.h>

#define S_LEN 4096
#define HIDN  1024
#define NH    16
#define HD    64
#define BATCH 2
#define M_TOTAL (BATCH * S_LEN)   // 8192
#define N_RKV   (3 * HIDN)        // 3072
#define CS 128
#define NC (S_LEN / CS)           // 32

typedef __attribute__((ext_vector_type(8))) _Float16 f16x8;
typedef __attribute__((ext_vector_type(4))) float f32x4;
typedef __attribute__((ext_vector_type(4))) unsigned short u16x4;

// ---------- fp16 convert ----------
__device__ __forceinline__ unsigned short f2h(float x) {
    _Float16 h = (_Float16)x;
    return *(unsigned short*)&h;
}
__device__ __forceinline__ float h2f(unsigned short b) {
    _Float16 h = *(_Float16*)&b;
    return (float)h;
}

// ---------- async global->LDS, 16B per lane ----------
__device__ __forceinline__ void load_lds16(const void* g, void* l) {
    __builtin_amdgcn_global_load_lds((const __attribute__((address_space(1))) void*)g,
                                     (__attribute__((address_space(3))) void*)l, 16, 0, 0);
}

// ---------- K0: a = mean(exp(time_decay)) ----------
__global__ void k_avg_decay(const float* __restrict__ td, float* __restrict__ a_out) {
    int t = threadIdx.x;
    double acc = 0.0;
    for (int i = t; i < NH * HD; i += 64) acc += exp((double)td[i]);
    for (int off = 32; off > 0; off >>= 1) acc += __shfl_down(acc, off, 64);
    if (t == 0) a_out[0] = (float)(acc / (double)(NH * HD));
}

// ---------- K1a: mixed = hs*tm + shift(hs)*(1-tm) -> fp16 ----------
__global__ __launch_bounds__(256)
void k_split_mix(const float* __restrict__ hs, const float* __restrict__ tm,
                 unsigned short* __restrict__ Ah) {
    int g = blockIdx.x * 256 + threadIdx.x;      // over M_TOTAL * (HIDN/4)
    int kc = (g & 255) * 4;
    int m = g >> 8;
    float4 cur = *(const float4*)&hs[(size_t)m * HIDN + kc];
    float4 t4  = *(const float4*)&tm[kc];
    float4 prev = make_float4(0.f, 0.f, 0.f, 0.f);
    if (m & (S_LEN - 1)) prev = *(const float4*)&hs[(size_t)(m - 1) * HIDN + kc];
    u16x4 h;
    h.x = f2h(cur.x * t4.x + prev.x * (1.f - t4.x));
    h.y = f2h(cur.y * t4.y + prev.y * (1.f - t4.y));
    h.z = f2h(cur.z * t4.z + prev.z * (1.f - t4.z));
    h.w = f2h(cur.w * t4.w + prev.w * (1.f - t4.w));
    *(u16x4*)&Ah[(size_t)m * HIDN + kc] = h;
}

// ---------- K1b: flat fp32 -> fp16 (weights) ----------
__global__ __launch_bounds__(256)
void k_split_w(const float* __restrict__ W, unsigned short* __restrict__ Wh) {
    int g = blockIdx.x * 256 + threadIdx.x;
    size_t o = (size_t)g * 4;
    float4 v = *(const float4*)&W[o];
    u16x4 h;
    h.x = f2h(v.x); h.y = f2h(v.y); h.z = f2h(v.z); h.w = f2h(v.w);
    *(u16x4*)&Wh[o] = h;
}

__device__ __forceinline__ f32x4 mfma16(f16x8 a, f16x8 b, f32x4 c) {
    return __builtin_amdgcn_mfma_f32_16x16x32_f16(a, b, c, 0, 0, 0);
}

// ======================================================================
// GEMM1, 8-phase schedule (T2+T3+T4+T5): rkv = Ah(8192x1024) * Wrh^T -> fp16
// BM=256 BN=192 BK=64; 512 thr = 8 waves (2M x 4N); per-wave C = 128x48.
// LDS: 2 buffers x (A 32KB + B 24KB) = 112 KB. Units = 64 rows x 128 B,
// staged 1 global_load_lds instr/wave each. Per K-tile: A units 0-3, B 0-2.
//
// Steady staging ledger (iteration computes K-tiles t=2it [buf0], t+1 [buf1]):
//   ph1: A1,A3(t+1)->buf1   (buf1 A rows 64-127/192-255 last read prev ph7/8)
//   ph2: B0,B1(t+2)->buf0   (buf0 B read entirely at ph1)
//   ph3: B2(t+2), A0(t+2)   (buf0 A rows 0-63 read ph1-2)
//   ph4: A2(t+2)            (rows 128-191 read ph1-2)   + vmcnt(5) before bar2
//   ph5: A1,A3(t+2)->buf0   (rows 64-127/192-255 read ph3-4)
//   ph6: B0,B1(t+3)->buf1   (buf1 B read at ph5)
//   ph7: B2(t+3), A0(t+3)   (buf1 A0 read ph5-6)
//   ph8: A2(t+3)                                        + vmcnt(5) before bar2
// vmcnt(5) @ph4: outstanding = ph2(2)+ph3(2)+ph4(1)=5 -> tile t+1 landed.
// vmcnt(5) @ph8: outstanding 7 -> wait to 5 retires through ph5 -> next-iter
//   ph1 (needs ph2-4 stages) and ph3 (needs ph5 stage) both covered.
// B-frags register-cached per K-tile (read only ph1/ph5) -> B LDS frees at ph2/ph6.
// vmcnt placed BEFORE the barrier so all waves' DMA proven landed at barrier exit.
// ======================================================================
#define SBAR  do { __builtin_amdgcn_sched_barrier(0); __builtin_amdgcn_s_barrier(); \
                   __builtin_amdgcn_sched_barrier(0); } while (0)
#define LGKM0 do { asm volatile("s_waitcnt lgkmcnt(0)" ::: "memory"); \
                   __builtin_amdgcn_sched_barrier(0); } while (0)
#define VMC(n) asm volatile("s_waitcnt vmcnt(" #n ")" ::: "memory")

__global__ __launch_bounds__(512, 2)
void k_gemm1_8ph(const unsigned short* __restrict__ A,
                 const unsigned short* __restrict__ Bm,
                 unsigned short* __restrict__ C)
{
    __shared__ unsigned short smem[57344];   // 112 KB
    const int tid  = threadIdx.x;
    const int lane = tid & 63;
    const int wv   = tid >> 6;               // 0..7
    const int wm = wv >> 2, wn = wv & 3;
    const int lm = lane & 15, rq = lane >> 4;
    const int swz = (lm & 7) << 4;

    // bijective XCD swizzle (512 % 8 == 0)
    const int cpx = gridDim.x >> 3;          // 64
    const int wg  = (blockIdx.x & 7) * cpx + (blockIdx.x >> 3);
    const int bx  = wg & 15;                 // 16 N-blocks
    const int by  = wg >> 4;                 // 32 M-blocks
    const int m0 = by * 256, n0 = bx * 192;

    // staging source (inverse-swizzled column so linear DMA + swizzled read agree)
    const int srow = 8 * wv + (lane >> 3);
    const int scol = ((lane & 7) ^ (lane >> 3)) * 8;
    const unsigned short* sA = A  + (size_t)(m0 + srow) * 1024 + scol;
    const unsigned short* sB = Bm + (size_t)(n0 + srow) * 1024 + scol;
    unsigned short* dA = smem + wv * 512;            // +bf*28672 +u*4096 (shorts)
    unsigned short* dB = smem + 16384 + wv * 512;

#define STG_A(u, T, bf) load_lds16(sA + (u)*65536 + (T)*64, dA + (bf)*28672 + (u)*4096)
#define STG_B(u, T, bf) load_lds16(sB + (u)*65536 + (T)*64, dB + (bf)*28672 + (u)*4096)

    const int arow = (wm * 128 + lm) * 128 + rq * 16;    // byte base in A region
    int boff[3][2];
#pragma unroll
    for (int nt = 0; nt < 3; ++nt)
#pragma unroll
        for (int kk = 0; kk < 2; ++kk)
            boff[nt][kk] = (((wn * 48 + nt * 16 + lm) * 128 + rq * 16 + kk * 64) ^ swz);

    f16x8 aF[2][2], bF[3][2];
    f32x4 acc[8][3] = {};

#define READ_A(q, bf) { const char* Ab = (const char*)smem + (bf)*57344; \
    _Pragma("unroll") for (int m2 = 0; m2 < 2; ++m2) \
    _Pragma("unroll") for (int kk = 0; kk < 2; ++kk) \
        aF[m2][kk] = *(const f16x8*)(Ab + ((arow + (q)*4096 + m2*2048 + kk*64) ^ swz)); }

#define READ_B(bf) { const char* Bb = (const char*)smem + (bf)*57344 + 32768; \
    _Pragma("unroll") for (int nt = 0; nt < 3; ++nt) \
    _Pragma("unroll") for (int kk = 0; kk < 2; ++kk) \
        bF[nt][kk] = *(const f16x8*)(Bb + boff[nt][kk]); }

#define MMQ(q) { __builtin_amdgcn_s_setprio(1); \
    _Pragma("unroll") for (int kk = 0; kk < 2; ++kk) \
    _Pragma("unroll") for (int m2 = 0; m2 < 2; ++m2) \
    _Pragma("unroll") for (int nt = 0; nt < 3; ++nt) \
        acc[(q)*2+m2][nt] = mfma16(aF[m2][kk], bF[nt][kk], acc[(q)*2+m2][nt]); \
    __builtin_amdgcn_s_setprio(0); }

    // ---- prologue: tile0 full (7), tile1 partial B0-2,A0,A2 (5); tile0 landed
    STG_A(0,0,0); STG_A(1,0,0); STG_A(2,0,0); STG_A(3,0,0);
    STG_B(0,0,0); STG_B(1,0,0); STG_B(2,0,0);
    STG_B(0,1,1); STG_B(1,1,1); STG_B(2,1,1);
    STG_A(0,1,1); STG_A(2,1,1);
    VMC(5);
    SBAR;

    for (int it = 0; it < 8; ++it) {
        const int t = 2 * it;
        const bool st = (it < 7);
        // phase 1 (tile t, buf0, q0; reads B)
        READ_A(0, 0); READ_B(0);
        STG_A(1, t + 1, 1); STG_A(3, t + 1, 1);
        SBAR; LGKM0; MMQ(0); SBAR;
        // phase 2
        READ_A(1, 0);
        if (st) { STG_B(0, t + 2, 0); STG_B(1, t + 2, 0); }
        SBAR; LGKM0; MMQ(1); SBAR;
        // phase 3
        READ_A(2, 0);
        if (st) { STG_B(2, t + 2, 0); STG_A(0, t + 2, 0); }
        SBAR; LGKM0; MMQ(2); SBAR;
        // phase 4 + checkpoint (tile t+1 landed before any wave enters ph5)
        READ_A(3, 0);
        if (st) { STG_A(2, t + 2, 0); }
        SBAR; LGKM0; MMQ(3);
        if (st) { VMC(5); } else { VMC(0); }
        SBAR;
        // phase 5 (tile t+1, buf1, q0; reads B)
        READ_A(0, 1); READ_B(1);
        if (st) { STG_A(1, t + 2, 0); STG_A(3, t + 2, 0); }
        SBAR; LGKM0; MMQ(0); SBAR;
        // phase 6
        READ_A(1, 1);
        if (st) { STG_B(0, t + 3, 1); STG_B(1, t + 3, 1); }
        SBAR; LGKM0; MMQ(1); SBAR;
        // phase 7
        READ_A(2, 1);
        if (st) { STG_B(2, t + 3, 1); STG_A(0, t + 3, 1); }
        SBAR; LGKM0; MMQ(2); SBAR;
        // phase 8 + checkpoint
        READ_A(3, 1);
        if (st) { STG_A(2, t + 3, 1); }
        SBAR; LGKM0; MMQ(3);
        if (st) { VMC(5); }
        SBAR;
    }

    // ---- epilogue: fp16 C write
#pragma unroll
    for (int mt = 0; mt < 8; ++mt)
#pragma unroll
        for (int nt = 0; nt < 3; ++nt) {
            int col = n0 + wn * 48 + nt * 16 + lm;
#pragma unroll
            for (int r = 0; r < 4; ++r) {
                int row = m0 + wm * 128 + mt * 16 + rq * 4 + r;
                C[(size_t)row * N_RKV + col] = f2h(acc[mt][nt][r]);
            }
        }
}

// ---------- GEMM2: 128x128 dbuf MFMA GEMM (unchanged, proven) ----------
template<int LDC, int NBX, bool HALF_OUT>
__global__ __launch_bounds__(256, 2)
void k_gemm_bt(const unsigned short* __restrict__ A,
               const unsigned short* __restrict__ Bm,
               void* __restrict__ Cv)
{
    __shared__ unsigned short smem[16384];       // 32 KB: two 8192-elem buffers
    const int tid  = threadIdx.x;
    const int lane = tid & 63;
    const int wave = tid >> 6;
    const int wm = wave >> 1, wn = wave & 1;

    const int cpx = gridDim.x >> 3;
    const int wg  = (blockIdx.x & 7) * cpx + (blockIdx.x >> 3);
    const int bx  = wg % NBX;
    const int by  = wg / NBX;
    const int m0 = by * 128;
    const int n0 = bx * 128;

    const unsigned short* segsrc[4];
    int segdst[4];
    {
        int rowoff = lane >> 2;
        int q = (lane & 3) ^ (rowoff & 3);
#pragma unroll
        for (int i = 0; i < 4; ++i) {
            int s = wave * 4 + i;
            const unsigned short* base = (s < 8) ? A : Bm;
            int row = (s < 8) ? (m0 + s * 16) : (n0 + (s - 8) * 16);
            segsrc[i] = base + (size_t)(row + rowoff) * 1024 + q * 8;
            segdst[i] = s * 512;
        }
    }

    const int lm = lane & 15;
    const int rq = lane >> 4;
    const int qx = rq ^ (lane & 3);
    int aoff[4], boff2[4];
#pragma unroll
    for (int t = 0; t < 4; ++t) {
        aoff[t]  = (wm * 64 + t * 16 + lm) * 32 + qx * 8;
        boff2[t] = 4096 + (wn * 64 + t * 16 + lm) * 32 + qx * 8;
    }

    f32x4 acc[4][4] = {};

#pragma unroll
    for (int i = 0; i < 4; ++i) load_lds16(segsrc[i], smem + segdst[i]);

    int p = 0;
    for (int kt = 0; kt < 1024; kt += 32) {
        __syncthreads();
        if (kt + 32 < 1024) {
#pragma unroll
            for (int i = 0; i < 4; ++i)
                load_lds16(segsrc[i] + kt + 32, smem + ((p ^ 1) * 8192 + segdst[i]));
        }
        const unsigned short* sb = smem + p * 8192;
        f16x8 fah[4], fb[4];
#pragma unroll
        for (int t = 0; t < 4; ++t) {
            fah[t] = *(const f16x8*)(sb + aoff[t]);
            fb[t]  = *(const f16x8*)(sb + boff2[t]);
        }
#pragma unroll
        for (int mt = 0; mt < 4; ++mt)
#pragma unroll
            for (int nt = 0; nt < 4; ++nt)
                acc[mt][nt] = mfma16(fah[mt], fb[nt], acc[mt][nt]);
        p ^= 1;
    }

#pragma unroll
    for (int mt = 0; mt < 4; ++mt)
#pragma unroll
        for (int nt = 0; nt < 4; ++nt) {
            int col = n0 + wn * 64 + nt * 16 + lm;
#pragma unroll
            for (int r = 0; r < 4; ++r) {
                int row = m0 + wm * 64 + mt * 16 + rq * 4 + r;
                if constexpr (HALF_OUT)
                    ((unsigned short*)Cv)[(size_t)row * LDC + col] = f2h(acc[mt][nt][r]);
                else
                    ((float*)Cv)[(size_t)row * LDC + col] = acc[mt][nt][r];
            }
        }
}

// ---------- K3: chunk decay sums Cb from rkv (RoPE'd k * v) ----------
__global__ __launch_bounds__(256)
void k_cb(const unsigned short* __restrict__ rkv,
          const float* __restrict__ cosp, const float* __restrict__ sinp,
          const float* __restrict__ a_ptr, float* __restrict__ Cb)
{
    __shared__ float Ls[4][64][4];
    int bid = blockIdx.x;                        // bh*NC + c
    int c  = bid & (NC - 1);
    int bh = bid >> 5;
    int b = bh >> 4, h = bh & 15;
    int lane = threadIdx.x & 63;
    int wave = threadIdx.x >> 6;
    int lm = lane & 15;
    int rs = lane >> 4;
    int d0 = lm * 4;
    float a = a_ptr[0];
    float sgn = (lm < 8) ? -1.f : 1.f;
    float ps0 = 0.f, ps1 = 0.f, ps2 = 0.f, ps3 = 0.f;
#pragma unroll
    for (int it = 0; it < 8; ++it) {
        int t = wave * 32 + it * 4 + rs;         // in-chunk row 0..127
        int s = c * CS + t;
        const unsigned short* rk = rkv + ((size_t)b * S_LEN + s) * N_RKV + h * 64 + d0;
        u16x4 k4 = *(const u16x4*)(rk + 1024);
        u16x4 v4 = *(const u16x4*)(rk + 2048);
        float4 cs4 = *(const float4*)&cosp[s * HD + d0];
        float4 sn4 = *(const float4*)&sinp[s * HD + d0];
        float e = expf(a * (float)t);
        float k0 = h2f(k4.x), k1 = h2f(k4.y), k2 = h2f(k4.z), k3 = h2f(k4.w);
        float kp0 = __shfl_xor(k0, 8, 64);
        float kp1 = __shfl_xor(k1, 8, 64);
        float kp2 = __shfl_xor(k2, 8, 64);
        float kp3 = __shfl_xor(k3, 8, 64);
        ps0 += e * (k0 * cs4.x + sgn * kp0 * sn4.x) * h2f(v4.x);
        ps1 += e * (k1 * cs4.y + sgn * kp1 * sn4.y) * h2f(v4.y);
        ps2 += e * (k2 * cs4.z + sgn * kp2 * sn4.z) * h2f(v4.z);
        ps3 += e * (k3 * cs4.w + sgn * kp3 * sn4.w) * h2f(v4.w);
    }
    Ls[wave][lane][0] = ps0; Ls[wave][lane][1] = ps1;
    Ls[wave][lane][2] = ps2; Ls[wave][lane][3] = ps3;
    __syncthreads();
    if (threadIdx.x < 64) {
        int d = threadIdx.x;
        int lmm = d >> 2, j = d & 3;
        float sum = 0.f;
#pragma unroll
        for (int wvv = 0; wvv < 4; ++wvv)
#pragma unroll
            for (int r = 0; r < 4; ++r)
                sum += Ls[wvv][r * 16 + lmm][j];
        Cb[((size_t)bh * NC + c) * 64 + d] = sum;
    }
}

// ---------- K5: exclusive chunk suffix ----------
__global__ __launch_bounds__(64)
void k_chunk_suffix(const float* __restrict__ Cb, const float* __restrict__ a_ptr,
                    float* __restrict__ Sb) {
    int bh = blockIdx.x;
    int d = threadIdx.x;
    float a = a_ptr[0];
    float eaCS = expf(a * (float)CS);
    float run = 0.f;
    Sb[(size_t)(bh * NC + NC - 1) * 64 + d] = 0.f;
    for (int c = NC - 2; c >= 0; --c) {
        run = Cb[(size_t)(bh * NC + c + 1) * 64 + d] + eaCS * run;
        Sb[(size_t)(bh * NC + c) * 64 + d] = run;
    }
}

// ---------- K5b: reciprocal normalizer table 1/Z ----------
__global__ __launch_bounds__(256)
void k_ztab(const float* __restrict__ a_ptr, float* __restrict__ Zt) {
    int i = blockIdx.x * 256 + threadIdx.x;
    if (i < S_LEN) {
        float a = a_ptr[0];
        float em1a = expm1f(a);
        Zt[i] = 1.f / (expm1f(a * (float)(S_LEN - i)) / em1a + 1e-8f);
    }
}

// ---------- K6: in-chunk suffix scan + epilogue, LDS-staged chunk tile ----------
__global__ __launch_bounds__(256)
void k_wkv2(const unsigned short* __restrict__ rkv,
            const float* __restrict__ cosp, const float* __restrict__ sinp,
            const float* __restrict__ Sb, const float* __restrict__ a_ptr,
            const float* __restrict__ tf, const float* __restrict__ Zt,
            unsigned short* __restrict__ outH) {
    __shared__ unsigned short L[3 * 128 * 64];   // 48 KB: r,k,v tiles [row][d]
    __shared__ float Tl[4][64];
    int bid = blockIdx.x;                // bh*NC + c
    int c  = bid & (NC - 1);
    int bh = bid >> 5;
    int b = bh >> 4, h = bh & 15;
    int lane = threadIdx.x & 63;
    int wave = threadIdx.x >> 6;
    int s0 = c * CS;

#pragma unroll
    for (int i = 0; i < 12; ++i) {
        int seg = wave * 12 + i;         // 0..47
        int stream = seg >> 4;           // 0=r 1=k 2=v
        int rg = seg & 15;               // 8-row group
        int row = rg * 8 + (lane >> 3);
        const unsigned short* src = rkv
            + ((size_t)b * S_LEN + s0 + row) * N_RKV + stream * 1024 + h * 64
            + (lane & 7) * 8;
        load_lds16(src, L + stream * 8192 + rg * 512);
    }
    __syncthreads();

    float a = a_ptr[0];
    float ea = expf(a);
    const unsigned short* Lr = L;
    const unsigned short* Lk = L + 8192;
    const unsigned short* Lv = L + 16384;
    float sgn = (lane < 32) ? -1.f : 1.f;
    int lx = lane ^ 32;

    float kvreg[32], rreg[32];
    float w = 1.f, T = 0.f;
#pragma unroll
    for (int t = 0; t < 32; ++t) {
        int row = wave * 32 + t;
        float r_ = h2f(Lr[row * 64 + lane]);
        float k_ = h2f(Lk[row * 64 + lane]);
        float kp = h2f(Lk[row * 64 + lx]);
        float v_ = h2f(Lv[row * 64 + lane]);
        float cs = cosp[(s0 + row) * HD + lane];
        float sn = sinp[(s0 + row) * HD + lane];
        float sig = 1.f / (1.f + expf(-r_));
        float sigp = __shfl_xor(sig, 32, 64);
        rreg[t]  = sig * cs + sgn * sigp * sn;
        kvreg[t] = (k_ * cs + sgn * kp * sn) * v_;
        T += w * kvreg[t];
        w *= ea;
    }
    Tl[wave][lane] = T;
    __syncthreads();

    float e32 = expf(a * 32.f);
    float S_run = Sb[(size_t)bid * 64 + lane] * expf(a * 32.f * (float)(3 - wave));
    float f = 1.f;
    for (int wp = wave + 1; wp < 4; ++wp) {
        S_run += f * Tl[wp][lane];
        f *= e32;
    }
    float tfv = tf[h * HD + lane];
#pragma unroll
    for (int t = 31; t >= 0; --t) {
        float kv = kvreg[t];
        S_run = kv + ea * S_run;
        int ig = s0 + wave * 32 + t;
        float o = rreg[t] * (tfv * kv + S_run * Zt[ig]);
        size_t m = (size_t)b * S_LEN + ig;
        outH[m * HIDN + h * HD + lane] = f2h(o);
    }
}

extern "C" void kernel_launch(void* const* d_in, const int* in_sizes, int n_in,
                              void* d_out, int out_size, void* d_ws, size_t ws_size,
                              hipStream_t stream) {
    const float* hs    = (const float*)d_in[0];
    const float* cosp  = (const float*)d_in[1];
    const float* sinp  = (const float*)d_in[2];
    const float* W_rkv = (const float*)d_in[3];
    const float* W_o   = (const float*)d_in[4];
    const float* td    = (const float*)d_in[5];
    const float* tf    = (const float*)d_in[6];
    const float* tm    = (const float*)d_in[7];
    float* out = (float*)d_out;

    // workspace layout (total 76,021,764 B — unchanged footprint)
    char* w = (char*)d_ws;
    unsigned short* rkvH = (unsigned short*)w;                    // 48 MiB [gemm1 -> cb,wkv2]
    unsigned short* Ah   = (unsigned short*)(w + 50331648);       // 16 MiB [mix -> gemm1]
    unsigned short* outH = (unsigned short*)(w + 50331648);       // aliases Ah (dead after gemm1)
    unsigned short* Wrh  = (unsigned short*)(w + 67108864);       // 6 MiB
    unsigned short* Woh  = (unsigned short*)(w + 73400320);       // 2 MiB
    float*          Cb   = (float*)(w + 75497472);                // 256 KiB
    float*          Sb   = (float*)(w + 75759616);                // 256 KiB
    float*          a_ptr= (float*)(w + 76021760);                // 4 B
    float*          Zt   = Cb;   // 16 KiB table; Cb dead after k_chunk_suffix

    k_avg_decay<<<1, 64, 0, stream>>>(td, a_ptr);

    k_split_mix<<<(M_TOTAL * HIDN / 4) / 256, 256, 0, stream>>>(hs, tm, Ah);
    k_split_w<<<(N_RKV * HIDN / 4) / 256, 256, 0, stream>>>(W_rkv, Wrh);
    k_split_w<<<(HIDN * HIDN / 4) / 256, 256, 0, stream>>>(W_o, Woh);

    // GEMM1: 8-phase 256x192 schedule
    k_gemm1_8ph<<<512, 512, 0, stream>>>(Ah, Wrh, rkvH);

    k_cb<<<BATCH * NH * NC, 256, 0, stream>>>(rkvH, cosp, sinp, a_ptr, Cb);
    k_chunk_suffix<<<BATCH * NH, 64, 0, stream>>>(Cb, a_ptr, Sb);
    k_ztab<<<S_LEN / 256, 256, 0, stream>>>(a_ptr, Zt);
    k_wkv2<<<BATCH * NH * NC, 256, 0, stream>>>(rkvH, cosp, sinp, Sb, a_ptr, tf, Zt, outH);

    // GEMM2: out = outH(8192x1024) * Woh(1024x1024)^T -> fp32
    k_gemm_bt<HIDN, 8, false><<<512, 256, 0, stream>>>(outH, Woh, out);
}